// Round 1
// 282.607 us; speedup vs baseline: 1.1047x; 1.1047x over previous
//
#include <hip/hip_runtime.h>
#include <stdint.h>

#define B_    8
#define A_    49104
#define C_    90
#define IMG_  512.0f
#define THR_  0.2f
#define KPRE  1000
#define KOUT  100
#define NCAND 1024   // ranked candidate count (power of two)
#define NKEY  2048   // sort buffer per image (LDS, power of two)
#define NBIN  1024   // histogram bins (fallback path)
#define BINBASE 0x17C99u     // f2ord(0.2f) >> 15
#define THRU    0xBE4CCCCDu  // f2ord(0.2f)
#define GANCH 64     // anchors per score block
#define PREF_F 0.9997f   // static prefilter: P(max of 90 U(0,1) >= .9997) ~ 2.7% -> n~1308/img

#define NPAD 1088            // 1024 + 64 pad (+1 float per 16) -> 17w+q bank pattern
#define PADI(j) ((j) + ((j) >> 4))

static __device__ __forceinline__ uint32_t f2ord(float f) {
    uint32_t b = __float_as_uint(f);
    return (b & 0x80000000u) ? ~b : (b | 0x80000000u);
}
static __device__ __forceinline__ float ord2f(uint32_t u) {
    uint32_t b = (u & 0x80000000u) ? (u & 0x7FFFFFFFu) : ~u;
    return __uint_as_float(b);
}

// ---------------------------------------------------------------- kernel 1
// streaming max/argmax over 90 classes + ballot-compacted prefilter.
// No box decode here: only ~1300 anchors/image survive the prefilter, so
// boxes/classes are materialized later for ranked candidates only.
// key64 layout: [score_ord:32][~idx:16][cls:8][0:8] -> descending sort ==
// (score desc, idx asc); cls rides along in dead bits.
__global__ __launch_bounds__(256)
void k_score_compact(const float* __restrict__ cls,
                     uint32_t* __restrict__ scores_u,
                     uint64_t* __restrict__ keybuf,
                     uint32_t* __restrict__ cntg) {
    __shared__ float4 s4[(GANCH * C_) / 4];          // 1440 float4 = 23040 B
    __shared__ float r_val[GANCH];
    __shared__ int   r_cls[GANCH];

    int tid = threadIdx.x;
    int b = blockIdx.y;
    int a0 = blockIdx.x * GANCH;
    int valid = A_ - a0; if (valid > GANCH) valid = GANCH;

    const float4* src = (const float4*)(cls + (size_t)(b * A_ + a0) * C_);
    if (valid == GANCH) {
        float4 v0 = src[tid];
        float4 v1 = src[tid + 256];
        float4 v2 = src[tid + 512];
        float4 v3 = src[tid + 768];
        float4 v4 = src[tid + 1024];
        float4 v5;
        if (tid < 160) v5 = src[tid + 1280];
        s4[tid]        = v0;
        s4[tid + 256]  = v1;
        s4[tid + 512]  = v2;
        s4[tid + 768]  = v3;
        s4[tid + 1024] = v4;
        if (tid < 160) s4[tid + 1280] = v5;
    } else {
        int n4 = (valid * C_) / 4;                   // valid multiple of 16 -> exact
        for (int i = tid; i < n4; i += 256) s4[i] = src[i];
    }
    __syncthreads();

    const float* s = (const float*)s4;
    int g = tid >> 2, sub = tid & 3;
    float best = -1.0f; int bi = 0;
    if (g < valid) {
        #pragma unroll
        for (int j = sub; j < C_ + 2; j += 4) {
            if (j < C_) {
                float v = s[g * C_ + j];
                if (v > best) { best = v; bi = j; }
            }
        }
    }
    #pragma unroll
    for (int d = 1; d < 4; d <<= 1) {
        float ov = __shfl_xor(best, d);
        int   oi = __shfl_xor(bi, d);
        if (ov > best || (ov == best && oi < bi)) { best = ov; bi = oi; }
    }
    if (sub == 0 && g < valid) { r_val[g] = best; r_cls[g] = bi; }
    __syncthreads();

    if (tid < 64) {                                  // wave 0 only
        int a = a0 + tid;
        bool v = tid < valid;
        float bv = v ? r_val[tid] : -1.0f;
        if (v) {
            float m = (bv > THR_) ? bv : -1.0f;
            scores_u[b * A_ + a] = f2ord(m);
        }
        bool flag = v && (bv >= PREF_F);
        unsigned long long mb = __ballot(flag);
        if (mb) {
            uint32_t base = 0;
            if (tid == 0) base = atomicAdd(&cntg[b], (uint32_t)__popcll(mb));
            base = (uint32_t)__shfl((int)base, 0);
            if (flag) {
                int p = (int)base + (int)__popcll(mb & ((1ull << tid) - 1ull));
                if (p < NKEY) {
                    uint64_t key = ((uint64_t)f2ord(bv) << 32)
                                 | ((uint64_t)((~(uint32_t)a) & 0xFFFFu) << 16)
                                 | ((uint64_t)(uint32_t)r_cls[tid] << 8);
                    keybuf[b * NKEY + p] = key;
                }
            }
        }
    }
}

// ---------------------------------------------------------------- kernel 2
// per-image: load compact keys (fast path) or exact histogram fallback,
// bitonic-sort 2048 keys descending (66 passes, replaces the O(n^2)
// rank-sort), then decode boxes/classes for the top NCAND ranks only.
__global__ __launch_bounds__(1024)
void k_seltop2(const uint32_t* __restrict__ scores_u,
               const float* __restrict__ cls,
               const float* __restrict__ loc,
               const float* __restrict__ anc,
               const uint64_t* __restrict__ keybuf,
               const uint32_t* __restrict__ cntg,
               float* __restrict__ cand_val,
               int* __restrict__ cand_cls,
               float* __restrict__ cand_box,
               int* __restrict__ n_valid) {
    int b = blockIdx.x;
    int t = threadIdx.x;                  // 1024
    __shared__ uint64_t keys[NKEY];       // 16 KB (fallback aliases h over it)
    __shared__ uint32_t sh_coarse;
    __shared__ int      sh_rem;
    __shared__ uint32_t sh_cutoff;
    __shared__ int      sh_cnt;
    const uint32_t* su = scores_u + (size_t)b * A_;

    int n = (int)cntg[b];                 // uniform across block
    bool fast = (n >= KPRE && n <= NKEY);

    if (fast) {
        for (int i = t; i < NKEY; i += 1024)
            keys[i] = (i < n) ? keybuf[b * NKEY + i] : 0ull;
    } else {
        // ---- exact fallback: coarse hist -> fine hist -> compact (dead path
        // statistically; kept bit-exact vs previous verified version)
        uint32_t* h = (uint32_t*)keys;    // alias: h dead before keys written
        h[t] = 0;
        if (t == 0) sh_cnt = 0;
        __syncthreads();
        for (int a = t; a < A_; a += 1024) {
            uint32_t u = su[a];
            if (u > THRU) {
                int bin = (int)(u >> 15) - (int)BINBASE;
                bin = bin < 0 ? 0 : (bin >= NBIN ? NBIN - 1 : bin);
                atomicAdd(&h[bin], 1u);
            }
        }
        __syncthreads();
        for (int d = 1; d < NBIN; d <<= 1) {
            uint32_t add = (t + d < NBIN) ? h[t + d] : 0u;
            __syncthreads();
            h[t] += add;
            __syncthreads();
        }
        {
            uint32_t St = h[t];
            uint32_t Sn = (t + 1 < NBIN) ? h[t + 1] : 0u;
            if (St >= KPRE && Sn < KPRE) {
                sh_coarse = (BINBASE + (uint32_t)t) << 15;
                sh_rem = KPRE - (int)Sn;
            }
            if (t == 0 && h[0] < KPRE) {
                sh_rem = 0;
                sh_coarse = 0xFFFFFFFFu;
                sh_cutoff = BINBASE << 15;
            }
        }
        __syncthreads();
        uint32_t coarse = sh_coarse;
        int rem = sh_rem;

        h[t] = 0;
        __syncthreads();
        if (rem > 0) {
            for (int a = t; a < A_; a += 1024) {
                uint32_t u = su[a];
                if ((u & 0xFFFF8000u) == coarse)
                    atomicAdd(&h[(u >> 5) & 0x3FF], 1u);
            }
        }
        __syncthreads();
        for (int d = 1; d < NBIN; d <<= 1) {
            uint32_t add = (t + d < NBIN) ? h[t + d] : 0u;
            __syncthreads();
            h[t] += add;
            __syncthreads();
        }
        if (rem > 0) {
            int St = (int)h[t];
            int Sn = (t + 1 < NBIN) ? (int)h[t + 1] : 0;
            if (St >= rem && Sn < rem)
                sh_cutoff = coarse | ((uint32_t)t << 5);
        }
        __syncthreads();
        uint32_t cutoff = sh_cutoff;
        __syncthreads();                  // all h reads done before keys reuse

        for (int a = t; a < A_; a += 1024) {
            uint32_t u = su[a];
            if (u >= cutoff) {
                int p = atomicAdd(&sh_cnt, 1);
                if (p < NKEY)
                    keys[p] = ((uint64_t)u << 32)
                            | ((uint64_t)((~(uint32_t)a) & 0xFFFFu) << 16);
            }
        }
        __syncthreads();
        n = sh_cnt; if (n > NKEY) n = NKEY;
        for (int i = t; i < NKEY; i += 1024)
            if (i >= n) keys[i] = 0ull;
    }
    __syncthreads();

    // ---- bitonic sort, descending (pads = 0 sink to the end). keys unique.
    for (int kk = 2; kk <= NKEY; kk <<= 1) {
        for (int jj = kk >> 1; jj > 0; jj >>= 1) {
            int i1 = ((t & ~(jj - 1)) << 1) | (t & (jj - 1));
            int i2 = i1 + jj;
            uint64_t va = keys[i1], vb = keys[i2];
            bool desc = ((i1 & kk) == 0);
            if ((va < vb) == desc) { keys[i1] = vb; keys[i2] = va; }
            __syncthreads();
        }
    }

    // ---- emit rank t: decode box + class for ranked candidates only
    uint64_t key = keys[t];
    bool real = (t < n);                  // sorted desc; first n are real
    int ci = b * NCAND + t;
    if (real) {
        int a = (int)((~(uint32_t)(key >> 16)) & 0xFFFFu);
        int c;
        if (fast) {
            c = (int)((key >> 8) & 0xFFu);
        } else {                          // fallback: recompute argmax (dead path)
            const float* row = cls + ((size_t)b * A_ + a) * C_;
            float bb = -1.0f; int bc = 0;
            for (int j = 0; j < C_; ++j) { float q = row[j]; if (q > bb) { bb = q; bc = j; } }
            c = bc;
        }
        float4 an = ((const float4*)anc)[a];
        float4 l4 = ((const float4*)loc)[(size_t)b * A_ + a];
        float ya = (an.x + an.z) * 0.5f;
        float xa = (an.y + an.w) * 0.5f;
        float ha = an.z - an.x;
        float wa = an.w - an.y;
        float hh = expf(l4.z) * ha;
        float ww = expf(l4.w) * wa;
        float yc = l4.x * ha + ya;
        float xc = l4.y * wa + xa;
        float4 bx;
        bx.x = fminf(fmaxf(xc - ww * 0.5f, 0.0f), IMG_);
        bx.y = fminf(fmaxf(yc - hh * 0.5f, 0.0f), IMG_);
        bx.z = fminf(fmaxf(xc + ww * 0.5f, 0.0f), IMG_);
        bx.w = fminf(fmaxf(yc + hh * 0.5f, 0.0f), IMG_);
        cand_val[ci] = ord2f((uint32_t)(key >> 32));
        cand_cls[ci] = c;
        ((float4*)cand_box)[ci] = bx;
    } else {
        cand_val[ci] = -1.0f;
        cand_cls[ci] = 0;
        float4 z; z.x = z.y = z.z = z.w = 0.0f;
        ((float4*)cand_box)[ci] = z;
    }
    if (t == 0) n_valid[b] = n < KPRE ? n : KPRE;
}

// ---------------------------------------------------------------- kernel 3
// IoU > 0.2 bitmask rows; lower triangle skipped. LDS arrays padded with
// +1 float per 16 (PADI): inner reads hit 17w+q -> all 32 banks (was a
// 32-way conflict at stride 16).
__global__ void k_masks(const float* __restrict__ cand_box,
                        const int* __restrict__ cand_cls,
                        unsigned short* __restrict__ M16) {
    int b = blockIdx.x;
    __shared__ float x1s[NPAD], y1s[NPAD], x2s[NPAD], y2s[NPAD], ars[NPAD];
    for (int i = threadIdx.x; i < NCAND; i += blockDim.x) {
        int ci = b * NCAND + i;
        float4 bx = ((const float4*)cand_box)[ci];
        float off = (float)cand_cls[ci] * (IMG_ + 1.0f);
        float ox1 = bx.x + off, oy1 = bx.y + off;
        float ox2 = bx.z + off, oy2 = bx.w + off;
        int ip = PADI(i);
        x1s[ip] = ox1; y1s[ip] = oy1; x2s[ip] = ox2; y2s[ip] = oy2;
        ars[ip] = (ox2 - ox1) * (oy2 - oy1);   // area AFTER offset, like the ref
    }
    __syncthreads();

    int row0 = blockIdx.y * 63;               // 16 chunks x 63 rows >= 1000
    for (int item = threadIdx.x; item < 63 * 64; item += blockDim.x) {
        int i = row0 + (item >> 6);
        if (i >= KPRE) continue;
        int w = item & 63;
        if (w < (i >> 4)) continue;           // dead words (cols <= i-16)
        int ip = PADI(i);
        float xi1 = x1s[ip], yi1 = y1s[ip], xi2 = x2s[ip], yi2 = y2s[ip], ai = ars[ip];
        unsigned int m = 0;
        int j0 = w * 16;
        #pragma unroll
        for (int q = 0; q < 16; ++q) {
            int jp = PADI(j0 + q);
            float xx1 = fmaxf(xi1, x1s[jp]);
            float yy1 = fmaxf(yi1, y1s[jp]);
            float xx2 = fminf(xi2, x2s[jp]);
            float yy2 = fminf(yi2, y2s[jp]);
            float iw = xx2 - xx1; iw = iw > 0.0f ? iw : 0.0f;
            float ih = yy2 - yy1; ih = ih > 0.0f ? ih : 0.0f;
            float inter = iw * ih;
            float den = (ai + ars[jp]) - inter + 1e-8f;   // ref associativity
            float iou = inter / den;
            m |= (iou > THR_ ? 1u : 0u) << q;
        }
        M16[((size_t)(b * NCAND + i)) * 64 + w] = (unsigned short)m;
    }
}

// ---------------------------------------------------------------- kernel 4
// sequential greedy NMS scan (1 wave/image) + output emit
__global__ void k_nms_out(const unsigned short* __restrict__ M16,
                          const float* __restrict__ cand_val,
                          const int* __restrict__ cand_cls,
                          const float* __restrict__ cand_box,
                          const int* __restrict__ n_valid,
                          float* __restrict__ out) {
    int b = blockIdx.x;
    int lane = threadIdx.x;  // 64
    int nv = n_valid[b]; if (nv > KPRE) nv = KPRE;
    const unsigned short* Mr = M16 + (size_t)b * NCAND * 64;
    __shared__ int kept[KOUT];

    uint32_t S = 0;          // 16 suppression bits per lane
    int cnt = 0;
    uint32_t cur[8], nxt[8];
    #pragma unroll
    for (int t = 0; t < 8; ++t) cur[t] = Mr[(size_t)t * 64 + lane];

    for (int base = 0; base < nv && cnt < KOUT; base += 8) {
        #pragma unroll
        for (int t = 0; t < 8; ++t) {
            int r = base + 8 + t;
            nxt[t] = Mr[(size_t)(r < NCAND ? r : 0) * 64 + lane];
        }
        #pragma unroll
        for (int t = 0; t < 8; ++t) {
            int i = base + t;
            bool inb = (i < nv) && (cnt < KOUT);
            unsigned long long ball =
                __ballot(inb && (((S >> (i & 15)) & 1u) != 0u));
            int sup = (int)((ball >> (i >> 4)) & 1ull);
            if (inb && !sup) {
                S |= cur[t];
                if (lane == 0) kept[cnt] = i;
                cnt++;
            }
        }
        #pragma unroll
        for (int t = 0; t < 8; ++t) cur[t] = nxt[t];
    }
    __syncthreads();

    for (int s_ = lane; s_ < KOUT; s_ += 64) {
        float b0 = 0.0f, b1 = 0.0f, b2 = 1.0f, b3 = 1.0f, sc = 0.0f, lb = -1.0f;
        if (s_ < cnt) {
            int i = kept[s_];
            int ci = b * NCAND + i;
            float4 bx = ((const float4*)cand_box)[ci];
            b0 = bx.x; b1 = bx.y; b2 = bx.z; b3 = bx.w;
            sc = cand_val[ci];
            lb = (float)cand_cls[ci];
        }
        int ob = (b * KOUT + s_) * 4;
        out[ob + 0] = b0; out[ob + 1] = b1; out[ob + 2] = b2; out[ob + 3] = b3;
        out[B_ * KOUT * 4 + b * KOUT + s_] = sc;          // scores
        out[B_ * KOUT * 5 + b * KOUT + s_] = lb;          // labels (as f32)
    }
}

// ----------------------------------------------------------------
extern "C" void kernel_launch(void* const* d_in, const int* in_sizes, int n_in,
                              void* d_out, int out_size, void* d_ws, size_t ws_size,
                              hipStream_t stream) {
    const float* cls = (const float*)d_in[0];
    const float* loc = (const float*)d_in[1];
    const float* anc = (const float*)d_in[2];
    float* out = (float*)d_out;

    char* ws = (char*)d_ws;
    size_t off = 0;
    auto alloc = [&](size_t bytes) -> void* {
        void* p = ws + off;
        off += (bytes + 255) & ~(size_t)255;
        return p;
    };
    uint32_t* scores_u = (uint32_t*)alloc((size_t)B_ * A_ * 4);
    uint64_t* keybuf   = (uint64_t*)alloc((size_t)B_ * NKEY * 8);
    uint32_t* cntg     = (uint32_t*)alloc((size_t)B_ * 4);
    float*    cand_val = (float*)   alloc((size_t)B_ * NCAND * 4);
    int*      cand_cls = (int*)     alloc((size_t)B_ * NCAND * 4);
    float*    cand_box = (float*)   alloc((size_t)B_ * NCAND * 4 * 4);
    int*      n_valid  = (int*)     alloc((size_t)B_ * 4);
    unsigned short* M16 = (unsigned short*)alloc((size_t)B_ * NCAND * 64 * 2);

    hipMemsetAsync(cntg, 0, (size_t)B_ * 4, stream);   // graph-capturable

    dim3 gD((A_ + GANCH - 1) / GANCH, B_);
    k_score_compact<<<gD, 256, 0, stream>>>(cls, scores_u, keybuf, cntg);
    k_seltop2<<<B_, 1024, 0, stream>>>(
        scores_u, cls, loc, anc, keybuf, cntg,
        cand_val, cand_cls, cand_box, n_valid);
    k_masks<<<dim3(B_, 16), 256, 0, stream>>>(cand_box, cand_cls, M16);
    k_nms_out<<<B_, 64, 0, stream>>>(
        M16, cand_val, cand_cls, cand_box, n_valid, out);
}

// Round 2
// 269.812 us; speedup vs baseline: 1.1571x; 1.0474x over previous
//
#include <hip/hip_runtime.h>
#include <stdint.h>

#define B_    8
#define A_    49104
#define C_    90
#define IMG_  512.0f
#define THR_  0.2f
#define KPRE  1000
#define KOUT  100
#define NCAND 1024   // ranked candidate count (power of two)
#define NKEY  2048   // sort size per image (power of two)
#define NBIN  1024   // histogram bins (fallback path)
#define BINBASE 0x17C99u     // f2ord(0.2f) >> 15
#define THRU    0xBE4CCCCDu  // f2ord(0.2f)
#define GANCH 64     // anchors per score block
#define NBLKX ((A_ + GANCH - 1) / GANCH)   // 768 score blocks per image
#define PREF_F 0.9997f   // static prefilter: mean n ~ 1308/img, 8.6 sigma above KPRE

#define NPAD 1088            // 1024 + 64 pad (+1 float per 16) -> 17w+q bank pattern
#define PADI(j) ((j) + ((j) >> 4))

static __device__ __forceinline__ uint32_t f2ord(float f) {
    uint32_t b = __float_as_uint(f);
    return (b & 0x80000000u) ? ~b : (b | 0x80000000u);
}
static __device__ __forceinline__ float ord2f(uint32_t u) {
    uint32_t b = (u & 0x80000000u) ? (u & 0x7FFFFFFFu) : ~u;
    return __uint_as_float(b);
}
static __device__ __forceinline__ uint64_t shflx64(uint64_t v, int m) {
    uint32_t lo = (uint32_t)v, hi = (uint32_t)(v >> 32);
    lo = (uint32_t)__shfl_xor((int)lo, m);
    hi = (uint32_t)__shfl_xor((int)hi, m);
    return ((uint64_t)hi << 32) | lo;
}

// ---------------------------------------------------------------- kernel 1
// streaming max/argmax over 90 classes + ballot-compacted prefilter into
// PER-BLOCK slots (blk_cnt written unconditionally -> no memset, no global
// atomic). key64: [score_ord:32][~idx:16][cls:8][0:8] -> descending sort
// == (score desc, idx asc); cls rides along in dead bits.
__global__ __launch_bounds__(256)
void k_score_compact(const float* __restrict__ cls,
                     uint32_t* __restrict__ scores_u,
                     uint64_t* __restrict__ blk_keys,
                     uint32_t* __restrict__ blk_cnt) {
    __shared__ float4 s4[(GANCH * C_) / 4];          // 1440 float4 = 23040 B
    __shared__ float r_val[GANCH];
    __shared__ int   r_cls[GANCH];

    int tid = threadIdx.x;
    int b = blockIdx.y;
    int bx = blockIdx.x;
    int a0 = bx * GANCH;
    int valid = A_ - a0; if (valid > GANCH) valid = GANCH;

    const float4* src = (const float4*)(cls + (size_t)(b * A_ + a0) * C_);
    if (valid == GANCH) {
        float4 v0 = src[tid];
        float4 v1 = src[tid + 256];
        float4 v2 = src[tid + 512];
        float4 v3 = src[tid + 768];
        float4 v4 = src[tid + 1024];
        float4 v5;
        if (tid < 160) v5 = src[tid + 1280];
        s4[tid]        = v0;
        s4[tid + 256]  = v1;
        s4[tid + 512]  = v2;
        s4[tid + 768]  = v3;
        s4[tid + 1024] = v4;
        if (tid < 160) s4[tid + 1280] = v5;
    } else {
        int n4 = (valid * C_) / 4;                   // valid multiple of 16 -> exact
        for (int i = tid; i < n4; i += 256) s4[i] = src[i];
    }
    __syncthreads();

    const float* s = (const float*)s4;
    int g = tid >> 2, sub = tid & 3;
    float best = -1.0f; int bi = 0;
    if (g < valid) {
        #pragma unroll
        for (int j = sub; j < C_ + 2; j += 4) {
            if (j < C_) {
                float v = s[g * C_ + j];
                if (v > best) { best = v; bi = j; }
            }
        }
    }
    #pragma unroll
    for (int d = 1; d < 4; d <<= 1) {
        float ov = __shfl_xor(best, d);
        int   oi = __shfl_xor(bi, d);
        if (ov > best || (ov == best && oi < bi)) { best = ov; bi = oi; }
    }
    if (sub == 0 && g < valid) { r_val[g] = best; r_cls[g] = bi; }
    __syncthreads();

    if (tid < 64) {                                  // wave 0 only
        int a = a0 + tid;
        bool v = tid < valid;
        float bv = v ? r_val[tid] : -1.0f;
        if (v) {
            float m = (bv > THR_) ? bv : -1.0f;
            scores_u[b * A_ + a] = f2ord(m);         // fallback path input
        }
        bool flag = v && (bv >= PREF_F);
        unsigned long long mb = __ballot(flag);
        if (flag) {
            int pos = (int)__popcll(mb & ((1ull << tid) - 1ull));
            uint64_t key = ((uint64_t)f2ord(bv) << 32)
                         | ((uint64_t)((~(uint32_t)a) & 0xFFFFu) << 16)
                         | ((uint64_t)(uint32_t)r_cls[tid] << 8);
            blk_keys[((size_t)(b * NBLKX + bx)) * GANCH + pos] = key;
        }
        if (tid == 0) blk_cnt[b * NBLKX + bx] = (uint32_t)__popcll(mb);
    }
}

// ---------------------------------------------------------------- kernel 2
// per-image: prefix-scan per-block counts -> gather compact keys (fast
// path) or exact histogram fallback; register-resident bitonic sort of
// 2048 keys (shfl for partner distance <=32 -> 28 barriers, was 66);
// decode boxes/classes for the top NCAND ranks only.
__global__ __launch_bounds__(1024)
void k_seltop2(const uint32_t* __restrict__ scores_u,
               const float* __restrict__ cls,
               const float* __restrict__ loc,
               const float* __restrict__ anc,
               const uint64_t* __restrict__ blk_keys,
               const uint32_t* __restrict__ blk_cnt,
               float* __restrict__ cand_val,
               int* __restrict__ cand_cls,
               float* __restrict__ cand_box,
               int* __restrict__ n_valid) {
    int b = blockIdx.x;
    int t = threadIdx.x;                  // 1024
    __shared__ uint64_t keys[NKEY];       // 16 KB (fallback aliases h over it)
    __shared__ uint32_t pc[1024];         // 4 KB prefix-scan scratch
    __shared__ uint32_t sh_coarse;
    __shared__ int      sh_rem;
    __shared__ uint32_t sh_cutoff;
    __shared__ int      sh_cnt;
    const uint32_t* su = scores_u + (size_t)b * A_;

    // ---- inclusive prefix scan of per-block counts (768 -> padded 1024)
    uint32_t own = (t < NBLKX) ? blk_cnt[b * NBLKX + t] : 0u;
    pc[t] = own;
    __syncthreads();
    for (int d = 1; d < 1024; d <<= 1) {
        uint32_t v = (t >= d) ? pc[t - d] : 0u;
        __syncthreads();
        pc[t] += v;
        __syncthreads();
    }
    int n = (int)pc[1023];
    bool fast = (n >= KPRE && n <= NKEY);

    if (fast) {
        if (t < NBLKX && own) {
            int base = (int)pc[t] - (int)own;
            const uint64_t* src = blk_keys + ((size_t)(b * NBLKX + t)) * GANCH;
            for (int j = 0; j < (int)own; ++j) keys[base + j] = src[j];
        }
        for (int i = t; i < NKEY; i += 1024)
            if (i >= n) keys[i] = 0ull;
    } else {
        // ---- exact fallback: coarse hist -> fine hist -> compact (dead path
        // statistically; bit-exact vs previously verified version)
        uint32_t* h = (uint32_t*)keys;    // alias: h dead before keys written
        h[t] = 0;
        if (t == 0) sh_cnt = 0;
        __syncthreads();
        for (int a = t; a < A_; a += 1024) {
            uint32_t u = su[a];
            if (u > THRU) {
                int bin = (int)(u >> 15) - (int)BINBASE;
                bin = bin < 0 ? 0 : (bin >= NBIN ? NBIN - 1 : bin);
                atomicAdd(&h[bin], 1u);
            }
        }
        __syncthreads();
        for (int d = 1; d < NBIN; d <<= 1) {
            uint32_t add = (t + d < NBIN) ? h[t + d] : 0u;
            __syncthreads();
            h[t] += add;
            __syncthreads();
        }
        {
            uint32_t St = h[t];
            uint32_t Sn = (t + 1 < NBIN) ? h[t + 1] : 0u;
            if (St >= KPRE && Sn < KPRE) {
                sh_coarse = (BINBASE + (uint32_t)t) << 15;
                sh_rem = KPRE - (int)Sn;
            }
            if (t == 0 && h[0] < KPRE) {
                sh_rem = 0;
                sh_coarse = 0xFFFFFFFFu;
                sh_cutoff = BINBASE << 15;
            }
        }
        __syncthreads();
        uint32_t coarse = sh_coarse;
        int rem = sh_rem;

        h[t] = 0;
        __syncthreads();
        if (rem > 0) {
            for (int a = t; a < A_; a += 1024) {
                uint32_t u = su[a];
                if ((u & 0xFFFF8000u) == coarse)
                    atomicAdd(&h[(u >> 5) & 0x3FF], 1u);
            }
        }
        __syncthreads();
        for (int d = 1; d < NBIN; d <<= 1) {
            uint32_t add = (t + d < NBIN) ? h[t + d] : 0u;
            __syncthreads();
            h[t] += add;
            __syncthreads();
        }
        if (rem > 0) {
            int St = (int)h[t];
            int Sn = (t + 1 < NBIN) ? (int)h[t + 1] : 0;
            if (St >= rem && Sn < rem)
                sh_cutoff = coarse | ((uint32_t)t << 5);
        }
        __syncthreads();
        uint32_t cutoff = sh_cutoff;
        __syncthreads();                  // all h reads done before keys reuse

        for (int a = t; a < A_; a += 1024) {
            uint32_t u = su[a];
            if (u >= cutoff) {
                int p = atomicAdd(&sh_cnt, 1);
                if (p < NKEY)
                    keys[p] = ((uint64_t)u << 32)
                            | ((uint64_t)((~(uint32_t)a) & 0xFFFFu) << 16);
            }
        }
        __syncthreads();
        n = sh_cnt; if (n > NKEY) n = NKEY;
        for (int i = t; i < NKEY; i += 1024)
            if (i >= n) keys[i] = 0ull;
    }
    __syncthreads();

    // ---- register-resident bitonic sort, descending. Thread t holds
    // elements t (x) and t+1024 (y). Partner distance jj<=32 -> same wave
    // (shfl, no barrier); jj==1024 -> own x/y swap; jj in {64..512} -> LDS.
    // Waves race through shfl passes safely: pre-LDS, each wave only
    // touches its own 64+64 LDS slots. Keys unique (idx) -> exact order.
    uint64_t x = keys[t], y = keys[t + 1024];
    for (int kk = 2; kk <= NKEY; kk <<= 1) {
        for (int jj = kk >> 1; jj > 0; jj >>= 1) {
            if (jj == 1024) {             // partner of x is own y; desc region
                uint64_t mx = x > y ? x : y;
                uint64_t mn = x > y ? y : x;
                x = mx; y = mn;
                continue;
            }
            uint64_t px, py;
            if (jj >= 64) {
                keys[t] = x; keys[t + 1024] = y;
                __syncthreads();
                px = keys[t ^ jj]; py = keys[(t + 1024) ^ jj];
                __syncthreads();
            } else {
                px = shflx64(x, jj);
                py = shflx64(y, jj);
            }
            bool kmx = (((t & kk) == 0) == ((t & jj) == 0));
            x = kmx ? (x > px ? x : px) : (x > px ? px : x);
            int ty = t + 1024;
            bool kmy = (((ty & kk) == 0) == ((ty & jj) == 0));
            y = kmy ? (y > py ? y : py) : (y > py ? py : y);
        }
    }

    // ---- emit rank t (thread t holds rank-t key in x)
    uint64_t key = x;
    bool real = (t < n);                  // sorted desc; first n are real
    int ci = b * NCAND + t;
    if (real) {
        int a = (int)((~(uint32_t)(key >> 16)) & 0xFFFFu);
        int c;
        if (fast) {
            c = (int)((key >> 8) & 0xFFu);
        } else {                          // fallback: recompute argmax (dead path)
            const float* row = cls + ((size_t)b * A_ + a) * C_;
            float bb = -1.0f; int bc = 0;
            for (int j = 0; j < C_; ++j) { float q = row[j]; if (q > bb) { bb = q; bc = j; } }
            c = bc;
        }
        float4 an = ((const float4*)anc)[a];
        float4 l4 = ((const float4*)loc)[(size_t)b * A_ + a];
        float ya = (an.x + an.z) * 0.5f;
        float xa = (an.y + an.w) * 0.5f;
        float ha = an.z - an.x;
        float wa = an.w - an.y;
        float hh = expf(l4.z) * ha;
        float ww = expf(l4.w) * wa;
        float yc = l4.x * ha + ya;
        float xc = l4.y * wa + xa;
        float4 bx;
        bx.x = fminf(fmaxf(xc - ww * 0.5f, 0.0f), IMG_);
        bx.y = fminf(fmaxf(yc - hh * 0.5f, 0.0f), IMG_);
        bx.z = fminf(fmaxf(xc + ww * 0.5f, 0.0f), IMG_);
        bx.w = fminf(fmaxf(yc + hh * 0.5f, 0.0f), IMG_);
        cand_val[ci] = ord2f((uint32_t)(key >> 32));
        cand_cls[ci] = c;
        ((float4*)cand_box)[ci] = bx;
    } else {
        cand_val[ci] = -1.0f;
        cand_cls[ci] = 0;
        float4 z; z.x = z.y = z.z = z.w = 0.0f;
        ((float4*)cand_box)[ci] = z;
    }
    if (t == 0) n_valid[b] = n < KPRE ? n : KPRE;
}

// ---------------------------------------------------------------- kernel 3
// IoU > 0.2 bitmask rows; lower triangle skipped. LDS arrays padded with
// +1 float per 16 (PADI): inner reads hit 17w+q -> all 32 banks.
__global__ void k_masks(const float* __restrict__ cand_box,
                        const int* __restrict__ cand_cls,
                        unsigned short* __restrict__ M16) {
    int b = blockIdx.x;
    __shared__ float x1s[NPAD], y1s[NPAD], x2s[NPAD], y2s[NPAD], ars[NPAD];
    for (int i = threadIdx.x; i < NCAND; i += blockDim.x) {
        int ci = b * NCAND + i;
        float4 bx = ((const float4*)cand_box)[ci];
        float off = (float)cand_cls[ci] * (IMG_ + 1.0f);
        float ox1 = bx.x + off, oy1 = bx.y + off;
        float ox2 = bx.z + off, oy2 = bx.w + off;
        int ip = PADI(i);
        x1s[ip] = ox1; y1s[ip] = oy1; x2s[ip] = ox2; y2s[ip] = oy2;
        ars[ip] = (ox2 - ox1) * (oy2 - oy1);   // area AFTER offset, like the ref
    }
    __syncthreads();

    int row0 = blockIdx.y * 63;               // 16 chunks x 63 rows >= 1000
    for (int item = threadIdx.x; item < 63 * 64; item += blockDim.x) {
        int i = row0 + (item >> 6);
        if (i >= KPRE) continue;
        int w = item & 63;
        if (w < (i >> 4)) continue;           // dead words (cols <= i-16)
        int ip = PADI(i);
        float xi1 = x1s[ip], yi1 = y1s[ip], xi2 = x2s[ip], yi2 = y2s[ip], ai = ars[ip];
        unsigned int m = 0;
        int j0 = w * 16;
        #pragma unroll
        for (int q = 0; q < 16; ++q) {
            int jp = PADI(j0 + q);
            float xx1 = fmaxf(xi1, x1s[jp]);
            float yy1 = fmaxf(yi1, y1s[jp]);
            float xx2 = fminf(xi2, x2s[jp]);
            float yy2 = fminf(yi2, y2s[jp]);
            float iw = xx2 - xx1; iw = iw > 0.0f ? iw : 0.0f;
            float ih = yy2 - yy1; ih = ih > 0.0f ? ih : 0.0f;
            float inter = iw * ih;
            float den = (ai + ars[jp]) - inter + 1e-8f;   // ref associativity
            float iou = inter / den;
            m |= (iou > THR_ ? 1u : 0u) << q;
        }
        M16[((size_t)(b * NCAND + i)) * 64 + w] = (unsigned short)m;
    }
}

// ---------------------------------------------------------------- kernel 4
// sequential greedy NMS scan (1 wave/image) + output emit
__global__ void k_nms_out(const unsigned short* __restrict__ M16,
                          const float* __restrict__ cand_val,
                          const int* __restrict__ cand_cls,
                          const float* __restrict__ cand_box,
                          const int* __restrict__ n_valid,
                          float* __restrict__ out) {
    int b = blockIdx.x;
    int lane = threadIdx.x;  // 64
    int nv = n_valid[b]; if (nv > KPRE) nv = KPRE;
    const unsigned short* Mr = M16 + (size_t)b * NCAND * 64;
    __shared__ int kept[KOUT];

    uint32_t S = 0;          // 16 suppression bits per lane
    int cnt = 0;
    uint32_t cur[8], nxt[8];
    #pragma unroll
    for (int t = 0; t < 8; ++t) cur[t] = Mr[(size_t)t * 64 + lane];

    for (int base = 0; base < nv && cnt < KOUT; base += 8) {
        #pragma unroll
        for (int t = 0; t < 8; ++t) {
            int r = base + 8 + t;
            nxt[t] = Mr[(size_t)(r < NCAND ? r : 0) * 64 + lane];
        }
        #pragma unroll
        for (int t = 0; t < 8; ++t) {
            int i = base + t;
            bool inb = (i < nv) && (cnt < KOUT);
            unsigned long long ball =
                __ballot(inb && (((S >> (i & 15)) & 1u) != 0u));
            int sup = (int)((ball >> (i >> 4)) & 1ull);
            if (inb && !sup) {
                S |= cur[t];
                if (lane == 0) kept[cnt] = i;
                cnt++;
            }
        }
        #pragma unroll
        for (int t = 0; t < 8; ++t) cur[t] = nxt[t];
    }
    __syncthreads();

    for (int s_ = lane; s_ < KOUT; s_ += 64) {
        float b0 = 0.0f, b1 = 0.0f, b2 = 1.0f, b3 = 1.0f, sc = 0.0f, lb = -1.0f;
        if (s_ < cnt) {
            int i = kept[s_];
            int ci = b * NCAND + i;
            float4 bx = ((const float4*)cand_box)[ci];
            b0 = bx.x; b1 = bx.y; b2 = bx.z; b3 = bx.w;
            sc = cand_val[ci];
            lb = (float)cand_cls[ci];
        }
        int ob = (b * KOUT + s_) * 4;
        out[ob + 0] = b0; out[ob + 1] = b1; out[ob + 2] = b2; out[ob + 3] = b3;
        out[B_ * KOUT * 4 + b * KOUT + s_] = sc;          // scores
        out[B_ * KOUT * 5 + b * KOUT + s_] = lb;          // labels (as f32)
    }
}

// ----------------------------------------------------------------
extern "C" void kernel_launch(void* const* d_in, const int* in_sizes, int n_in,
                              void* d_out, int out_size, void* d_ws, size_t ws_size,
                              hipStream_t stream) {
    const float* cls = (const float*)d_in[0];
    const float* loc = (const float*)d_in[1];
    const float* anc = (const float*)d_in[2];
    float* out = (float*)d_out;

    char* ws = (char*)d_ws;
    size_t off = 0;
    auto alloc = [&](size_t bytes) -> void* {
        void* p = ws + off;
        off += (bytes + 255) & ~(size_t)255;
        return p;
    };
    uint32_t* scores_u = (uint32_t*)alloc((size_t)B_ * A_ * 4);
    uint64_t* blk_keys = (uint64_t*)alloc((size_t)B_ * NBLKX * GANCH * 8);
    uint32_t* blk_cnt  = (uint32_t*)alloc((size_t)B_ * NBLKX * 4);
    float*    cand_val = (float*)   alloc((size_t)B_ * NCAND * 4);
    int*      cand_cls = (int*)     alloc((size_t)B_ * NCAND * 4);
    float*    cand_box = (float*)   alloc((size_t)B_ * NCAND * 4 * 4);
    int*      n_valid  = (int*)     alloc((size_t)B_ * 4);
    unsigned short* M16 = (unsigned short*)alloc((size_t)B_ * NCAND * 64 * 2);

    dim3 gD(NBLKX, B_);
    k_score_compact<<<gD, 256, 0, stream>>>(cls, scores_u, blk_keys, blk_cnt);
    k_seltop2<<<B_, 1024, 0, stream>>>(
        scores_u, cls, loc, anc, blk_keys, blk_cnt,
        cand_val, cand_cls, cand_box, n_valid);
    k_masks<<<dim3(B_, 16), 256, 0, stream>>>(cand_box, cand_cls, M16);
    k_nms_out<<<B_, 64, 0, stream>>>(
        M16, cand_val, cand_cls, cand_box, n_valid, out);
}